// Round 21
// baseline (126.574 us; speedup 1.0000x reference)
//
#include <hip/hip_runtime.h>
#include <cstdint>
#include <cstddef>

#define BATCH   4
#define SEQ     4096
#define HIDDEN  4096
#define RANK    512
#define OUTF    4096
#define SROWS   4097              // seq+1
#define MROWS   (BATCH * SROWS)   // 16388
#define NGRP    1025              // ceil(MROWS/16) groups in packed Q

typedef int v4i __attribute__((ext_vector_type(4)));
typedef float v4f __attribute__((ext_vector_type(4)));

// Packed fragment-major layout for int8 operands:
//   T[G][kc][r] = 16 bytes, addr = G*8192 + kc*256 + r*16
//   (G = row>>4, r = row&15, kc = 16-byte K-chunk index 0..31)
// A wave's MFMA fragment for K-step kt is the contiguous 1 KB at
// G*8192 + kt*1024, lane l -> (row l&15, quarter l>>4).

// ---------------------------------------------------------------------------
// Kernel 1: new_latent[b][r] = dot(new_x[b,0,:], B_weight[r,:])
// ---------------------------------------------------------------------------
__global__ void k_new_latent(const float* __restrict__ newx,
                             const float* __restrict__ Bw,
                             float* __restrict__ out_latent) {
    int wave = threadIdx.x >> 6;
    int lane = threadIdx.x & 63;
    int pair = blockIdx.x * 4 + wave;   // 0..2047
    int b = pair >> 9;
    int r = pair & 511;
    const float4* x4 = (const float4*)(newx + (size_t)b * HIDDEN);
    const float4* w4 = (const float4*)(Bw + (size_t)r * HIDDEN);
    float sum = 0.f;
#pragma unroll
    for (int j = 0; j < 16; ++j) {
        float4 xv = x4[lane + 64 * j];
        float4 wv = w4[lane + 64 * j];
        sum += xv.x * wv.x + xv.y * wv.y + xv.z * wv.z + xv.w * wv.w;
    }
#pragma unroll
    for (int off = 32; off >= 1; off >>= 1)
        sum += __shfl_xor(sum, off, 64);
    if (lane == 0) {
        out_latent[(size_t)(b * SROWS + SEQ) * RANK + r] = sum;
    }
}

// ---------------------------------------------------------------------------
// Kernel 2: per-row int8 quant + copy cached rows to output (nt); writes Qt
// in packed fragment-major layout. One wave per row.
// ---------------------------------------------------------------------------
__global__ void k_quant(const float* __restrict__ cached,
                        float* __restrict__ out_latent,
                        uint8_t* __restrict__ Qt,
                        float* __restrict__ scales) {
    int m = blockIdx.x * 4 + (threadIdx.x >> 6);   // 0..16387
    int lane = threadIdx.x & 63;
    int b = m / SROWS;
    int s = m - b * SROWS;
    const float* src = (s < SEQ) ? (cached + ((size_t)b * SEQ + s) * RANK)
                                 : (out_latent + (size_t)m * RANK);
    float4 v0 = ((const float4*)src)[lane];
    float4 v1 = ((const float4*)src)[64 + lane];
    float am = fmaxf(fmaxf(fmaxf(fabsf(v0.x), fabsf(v0.y)),
                           fmaxf(fabsf(v0.z), fabsf(v0.w))),
                     fmaxf(fmaxf(fabsf(v1.x), fabsf(v1.y)),
                           fmaxf(fabsf(v1.z), fabsf(v1.w))));
#pragma unroll
    for (int off = 32; off >= 1; off >>= 1)
        am = fmaxf(am, __shfl_xor(am, off, 64));
    am = fmaxf(am, 1e-8f);
    float scale = am / 127.0f;

    auto qp = [&](float x) -> uint32_t {
        float r = rintf(x / scale);          // round-half-even, matches jnp.round
        r = fminf(fmaxf(r, -128.0f), 127.0f);
        return (uint32_t)(uint8_t)(int8_t)(int)r;
    };
    uint32_t p0 = qp(v0.x) | (qp(v0.y) << 8) | (qp(v0.z) << 16) | (qp(v0.w) << 24);
    uint32_t p1 = qp(v1.x) | (qp(v1.y) << 8) | (qp(v1.z) << 16) | (qp(v1.w) << 24);

    int G = m >> 4, r = m & 15;
    uint32_t addr0 = (uint32_t)(G * 8192 + ((lane >> 2) << 8) + r * 16 + (lane & 3) * 4);
    *(uint32_t*)(Qt + addr0) = p0;
    *(uint32_t*)(Qt + addr0 + 4096) = p1;

    if (s < SEQ) {
        v4f* dst = (v4f*)(out_latent + (size_t)m * RANK);
        v4f w0 = { v0.x, v0.y, v0.z, v0.w };
        v4f w1 = { v1.x, v1.y, v1.z, v1.w };
        __builtin_nontemporal_store(w0, &dst[lane]);
        __builtin_nontemporal_store(w1, &dst[64 + lane]);
    }
    if (lane == 0) scales[m] = scale;
}

// ---------------------------------------------------------------------------
// Kernel 3: pack A_int8 (int32, 4096x512) -> packed fragment-major int8.
// ---------------------------------------------------------------------------
__global__ void k_packA(const int* __restrict__ Ai, uint8_t* __restrict__ At) {
    int t = blockIdx.x * blockDim.x + threadIdx.x;   // 0..524287
    int n = t >> 7;
    int q = t & 127;
    int4 v = ((const int4*)(Ai + (size_t)n * RANK))[q];
    uint32_t p = (uint32_t)(v.x & 0xff) | ((uint32_t)(v.y & 0xff) << 8) |
                 ((uint32_t)(v.z & 0xff) << 16) | ((uint32_t)(v.w & 0xff) << 24);
    int G = n >> 4, r = n & 15;
    uint32_t addr = (uint32_t)(G * 8192 + ((q >> 2) << 8) + r * 16 + (q & 3) * 4);
    *(uint32_t*)(At + addr) = p;
}

// ---------------------------------------------------------------------------
// Kernel 4: int8 GEMM + dequant — R20 structure (packed direct-reg, BN=64,
// swapped C^T MFMA, full-line epilogue via wave-private LDS transpose),
// with CACHED full-line stores (nt removed from stage 2).
// Completed store matrix: cached-partial 133 (RFO) / nt-partial 114.7 /
// nt-full-line 106.2 / cached-FULL-LINE = THIS. Fill evidence: cached
// full-line wave stores = 6.9 TB/s, FETCH~0 (no RFO, write-through) vs
// nt's ~3 TB/s drain. Packed contiguous loads + prefetch + 16-wave TLP
// should tolerate the L2 pollution that remains.
// ---------------------------------------------------------------------------
#define BM 128
#define BN 64
#define NT_N (OUTF / BN)   // 64
#define NKT  8

__launch_bounds__(256, 4)
__global__ void k_gemm(const uint8_t* __restrict__ Qt,
                       const uint8_t* __restrict__ At,
                       const float* __restrict__ scales,
                       const float* __restrict__ Ascale,
                       float* __restrict__ out,
                       int M) {
    __shared__ __align__(16) float Ct[4][64 * 36];   // 36 KiB total

    // XCD-bijective blockIdx swizzle (gridDim.x = 8256, % 8 == 0), tn-minor.
    int per = gridDim.x >> 3;
    int bid = blockIdx.x;
    int swz = (bid & 7) * per + (bid >> 3);
    int tn = swz & (NT_N - 1);
    int tm = swz >> 6;          // / NT_N

    int tid = threadIdx.x;
    int lane = tid & 63;
    int wave = tid >> 6;
    int wr = wave >> 1, wc = wave & 1;
    int m0 = tm * BM;
    int n0 = tn * BN;

    uint32_t l16 = (uint32_t)lane * 16;
    const uint8_t* ap[4];
    const uint8_t* bp[2];
#pragma unroll
    for (int mi = 0; mi < 4; ++mi) {
        int G = (m0 + wr * 64 + mi * 16) >> 4;
        if (G >= NGRP) G = NGRP - 1;           // tail clamp (store-masked)
        ap[mi] = Qt + (uint32_t)G * 8192 + l16;
    }
#pragma unroll
    for (int ni = 0; ni < 2; ++ni) {
        int H = (n0 + wc * 32 + ni * 16) >> 4;
        bp[ni] = At + (uint32_t)H * 8192 + l16;
    }

    v4i aF[2][4], bF[2][2];
#pragma unroll
    for (int x = 0; x < 4; ++x) aF[0][x] = *(const v4i*)(ap[x]);
#pragma unroll
    for (int x = 0; x < 2; ++x) bF[0][x] = *(const v4i*)(bp[x]);

    v4i acc[4][2] = {};
#pragma unroll
    for (int kt = 0; kt < NKT; ++kt) {
        const int cur = kt & 1;          // constant after unroll
        if (kt < NKT - 1) {
            const uint32_t off = (uint32_t)(kt + 1) * 1024;
#pragma unroll
            for (int x = 0; x < 4; ++x) aF[cur ^ 1][x] = *(const v4i*)(ap[x] + off);
#pragma unroll
            for (int x = 0; x < 2; ++x) bF[cur ^ 1][x] = *(const v4i*)(bp[x] + off);
        }
        // SWAPPED operands: C^T fragment (rows = n, cols = m)
#pragma unroll
        for (int mi = 0; mi < 4; ++mi)
#pragma unroll
            for (int ni = 0; ni < 2; ++ni)
                acc[mi][ni] = __builtin_amdgcn_mfma_i32_16x16x64_i8(
                    bF[cur][ni], aF[cur][mi], acc[mi][ni], 0, 0, 0);
    }

    // Epilogue stage 1: dequant into wave-private LDS tile [64][36].
    // C^T layout: m_local = mi*16 + (lane&15), n_local = ni*16 + 4*(lane>>4)+r.
    int cm = lane & 15;
    int qn = (lane >> 4) * 4;
#pragma unroll
    for (int mi = 0; mi < 4; ++mi) {
        int mm = m0 + wr * 64 + mi * 16 + cm;
        float sc = (mm < M) ? scales[mm] : 0.f;
#pragma unroll
        for (int ni = 0; ni < 2; ++ni) {
            int nl = ni * 16 + qn;
            v4f av = *(const v4f*)(Ascale + n0 + wc * 32 + nl);
            v4f w;
            w.x = (float)acc[mi][ni][0] * sc * av.x;
            w.y = (float)acc[mi][ni][1] * sc * av.y;
            w.z = (float)acc[mi][ni][2] * sc * av.z;
            w.w = (float)acc[mi][ni][3] * sc * av.w;
            *(v4f*)&Ct[wave][(mi * 16 + cm) * 36 + nl] = w;
        }
    }
    // Epilogue stage 2: row-major readback -> full-line CACHED stores.
    // lane -> row (lane>>3)+8i, cols (lane&7)*4; per instr: 8 rows x 128 B.
    int rrow = lane >> 3;
    int rcol = (lane & 7) * 4;
#pragma unroll
    for (int i = 0; i < 8; ++i) {
        int ml = rrow + 8 * i;
        v4f w = *(const v4f*)&Ct[wave][ml * 36 + rcol];
        int mm = m0 + wr * 64 + ml;
        if (mm < M)
            *(v4f*)(out + (size_t)mm * OUTF + n0 + wc * 32 + rcol) = w;
    }
}

// ---------------------------------------------------------------------------
extern "C" void kernel_launch(void* const* d_in, const int* in_sizes, int n_in,
                              void* d_out, int out_size, void* d_ws, size_t ws_size,
                              hipStream_t stream) {
    const float* new_x  = (const float*)d_in[0];
    const float* cached = (const float*)d_in[1];
    const float* Bw     = (const float*)d_in[2];
    const int*   Ai     = (const int*)d_in[3];
    const float* Ascale = (const float*)d_in[4];

    float* out = (float*)d_out;
    float* out_latent = out + (size_t)MROWS * OUTF;

    const size_t QT_BYTES = (size_t)NGRP * 8192;        // 8,396,800
    const size_t S_BYTES  = (size_t)MROWS * sizeof(float);
    uint8_t* Qt     = (uint8_t*)d_ws;
    float*   scales = (float*)((char*)d_ws + QT_BYTES);
    uint8_t* At     = (uint8_t*)((char*)d_ws + QT_BYTES + S_BYTES);

    k_new_latent<<<512, 256, 0, stream>>>(new_x, Bw, out_latent);
    k_quant<<<SROWS, 256, 0, stream>>>(cached, out_latent, Qt, scales);
    k_packA<<<(OUTF * RANK / 4) / 256, 256, 0, stream>>>(Ai, At);
    int nt_m = (MROWS + BM - 1) / BM;   // 129
    k_gemm<<<nt_m * NT_N, 256, 0, stream>>>(Qt, At, scales, Ascale, out, MROWS);
}

// Round 22
// 105.169 us; speedup vs baseline: 1.2035x; 1.2035x over previous
//
#include <hip/hip_runtime.h>
#include <cstdint>
#include <cstddef>

#define BATCH   4
#define SEQ     4096
#define HIDDEN  4096
#define RANK    512
#define OUTF    4096
#define SROWS   4097              // seq+1
#define MROWS   (BATCH * SROWS)   // 16388
#define NGRP    1025              // ceil(MROWS/16) groups in packed Q

typedef int v4i __attribute__((ext_vector_type(4)));
typedef float v4f __attribute__((ext_vector_type(4)));

// Packed fragment-major layout for int8 operands:
//   T[G][kc][r] = 16 bytes, addr = G*8192 + kc*256 + r*16
//   (G = row>>4, r = row&15, kc = 16-byte K-chunk index 0..31)
// A wave's MFMA fragment for K-step kt is the contiguous 1 KB at
// G*8192 + kt*1024, lane l -> (row l&15, quarter l>>4).

// ---------------------------------------------------------------------------
// Kernel 1 (merged): blocks 0..511  -> new_latent (b,r) dot products
//                    blocks 512..2559 -> pack A_int8 -> fragment-major int8
// The two halves are mutually independent; both must precede k_quant/k_gemm
// (guaranteed by stream ordering).
// ---------------------------------------------------------------------------
__global__ void k_prep(const float* __restrict__ newx,
                       const float* __restrict__ Bw,
                       float* __restrict__ out_latent,
                       const int* __restrict__ Ai,
                       uint8_t* __restrict__ At) {
    if (blockIdx.x < 512) {
        int wave = threadIdx.x >> 6;
        int lane = threadIdx.x & 63;
        int pair = blockIdx.x * 4 + wave;   // 0..2047
        int b = pair >> 9;
        int r = pair & 511;
        const float4* x4 = (const float4*)(newx + (size_t)b * HIDDEN);
        const float4* w4 = (const float4*)(Bw + (size_t)r * HIDDEN);
        float sum = 0.f;
#pragma unroll
        for (int j = 0; j < 16; ++j) {
            float4 xv = x4[lane + 64 * j];
            float4 wv = w4[lane + 64 * j];
            sum += xv.x * wv.x + xv.y * wv.y + xv.z * wv.z + xv.w * wv.w;
        }
#pragma unroll
        for (int off = 32; off >= 1; off >>= 1)
            sum += __shfl_xor(sum, off, 64);
        if (lane == 0) {
            out_latent[(size_t)(b * SROWS + SEQ) * RANK + r] = sum;
        }
    } else {
        int t = (blockIdx.x - 512) * 256 + threadIdx.x;   // 0..524287
        int n = t >> 7;
        int q = t & 127;
        int4 v = ((const int4*)(Ai + (size_t)n * RANK))[q];
        uint32_t p = (uint32_t)(v.x & 0xff) | ((uint32_t)(v.y & 0xff) << 8) |
                     ((uint32_t)(v.z & 0xff) << 16) | ((uint32_t)(v.w & 0xff) << 24);
        int G = n >> 4, r = n & 15;
        uint32_t addr = (uint32_t)(G * 8192 + ((q >> 2) << 8) + r * 16 + (q & 3) * 4);
        *(uint32_t*)(At + addr) = p;
    }
}

// ---------------------------------------------------------------------------
// Kernel 2: per-row int8 quant + copy cached rows to output (nt); writes Qt
// in packed fragment-major layout. One wave per row.
// ---------------------------------------------------------------------------
__global__ void k_quant(const float* __restrict__ cached,
                        float* __restrict__ out_latent,
                        uint8_t* __restrict__ Qt,
                        float* __restrict__ scales) {
    int m = blockIdx.x * 4 + (threadIdx.x >> 6);   // 0..16387
    int lane = threadIdx.x & 63;
    int b = m / SROWS;
    int s = m - b * SROWS;
    const float* src = (s < SEQ) ? (cached + ((size_t)b * SEQ + s) * RANK)
                                 : (out_latent + (size_t)m * RANK);
    float4 v0 = ((const float4*)src)[lane];
    float4 v1 = ((const float4*)src)[64 + lane];
    float am = fmaxf(fmaxf(fmaxf(fabsf(v0.x), fabsf(v0.y)),
                           fmaxf(fabsf(v0.z), fabsf(v0.w))),
                     fmaxf(fmaxf(fabsf(v1.x), fabsf(v1.y)),
                           fmaxf(fabsf(v1.z), fabsf(v1.w))));
#pragma unroll
    for (int off = 32; off >= 1; off >>= 1)
        am = fmaxf(am, __shfl_xor(am, off, 64));
    am = fmaxf(am, 1e-8f);
    float scale = am / 127.0f;

    auto qp = [&](float x) -> uint32_t {
        float r = rintf(x / scale);          // round-half-even, matches jnp.round
        r = fminf(fmaxf(r, -128.0f), 127.0f);
        return (uint32_t)(uint8_t)(int8_t)(int)r;
    };
    uint32_t p0 = qp(v0.x) | (qp(v0.y) << 8) | (qp(v0.z) << 16) | (qp(v0.w) << 24);
    uint32_t p1 = qp(v1.x) | (qp(v1.y) << 8) | (qp(v1.z) << 16) | (qp(v1.w) << 24);

    int G = m >> 4, r = m & 15;
    uint32_t addr0 = (uint32_t)(G * 8192 + ((lane >> 2) << 8) + r * 16 + (lane & 3) * 4);
    *(uint32_t*)(Qt + addr0) = p0;
    *(uint32_t*)(Qt + addr0 + 4096) = p1;

    if (s < SEQ) {
        v4f* dst = (v4f*)(out_latent + (size_t)m * RANK);
        v4f w0 = { v0.x, v0.y, v0.z, v0.w };
        v4f w1 = { v1.x, v1.y, v1.z, v1.w };
        __builtin_nontemporal_store(w0, &dst[lane]);
        __builtin_nontemporal_store(w1, &dst[64 + lane]);
    }
    if (lane == 0) scales[m] = scale;
}

// ---------------------------------------------------------------------------
// Kernel 3: int8 GEMM + dequant — CHAMPION STRUCTURE (R20): packed
// direct-reg, BN=64, swapped C^T MFMA, depth-1 reg prefetch, full-line
// NON-TEMPORAL stores via end-of-kernel wave-private LDS transpose.
// GEMM is write-drain-bound at the measured nt cap (~3.1 TB/s): store
// matrix fully explored (cached-partial 133 / nt-partial 114.7 /
// cached-full 126.6 / nt-full 106.2).
// ---------------------------------------------------------------------------
#define BM 128
#define BN 64
#define NT_N (OUTF / BN)   // 64
#define NKT  8

__launch_bounds__(256, 4)
__global__ void k_gemm(const uint8_t* __restrict__ Qt,
                       const uint8_t* __restrict__ At,
                       const float* __restrict__ scales,
                       const float* __restrict__ Ascale,
                       float* __restrict__ out,
                       int M) {
    __shared__ __align__(16) float Ct[4][64 * 36];   // 36 KiB total

    // XCD-bijective blockIdx swizzle (gridDim.x = 8256, % 8 == 0), tn-minor.
    int per = gridDim.x >> 3;
    int bid = blockIdx.x;
    int swz = (bid & 7) * per + (bid >> 3);
    int tn = swz & (NT_N - 1);
    int tm = swz >> 6;          // / NT_N

    int tid = threadIdx.x;
    int lane = tid & 63;
    int wave = tid >> 6;
    int wr = wave >> 1, wc = wave & 1;
    int m0 = tm * BM;
    int n0 = tn * BN;

    uint32_t l16 = (uint32_t)lane * 16;
    const uint8_t* ap[4];
    const uint8_t* bp[2];
#pragma unroll
    for (int mi = 0; mi < 4; ++mi) {
        int G = (m0 + wr * 64 + mi * 16) >> 4;
        if (G >= NGRP) G = NGRP - 1;           // tail clamp (store-masked)
        ap[mi] = Qt + (uint32_t)G * 8192 + l16;
    }
#pragma unroll
    for (int ni = 0; ni < 2; ++ni) {
        int H = (n0 + wc * 32 + ni * 16) >> 4;
        bp[ni] = At + (uint32_t)H * 8192 + l16;
    }

    v4i aF[2][4], bF[2][2];
#pragma unroll
    for (int x = 0; x < 4; ++x) aF[0][x] = *(const v4i*)(ap[x]);
#pragma unroll
    for (int x = 0; x < 2; ++x) bF[0][x] = *(const v4i*)(bp[x]);

    v4i acc[4][2] = {};
#pragma unroll
    for (int kt = 0; kt < NKT; ++kt) {
        const int cur = kt & 1;          // constant after unroll
        if (kt < NKT - 1) {
            const uint32_t off = (uint32_t)(kt + 1) * 1024;
#pragma unroll
            for (int x = 0; x < 4; ++x) aF[cur ^ 1][x] = *(const v4i*)(ap[x] + off);
#pragma unroll
            for (int x = 0; x < 2; ++x) bF[cur ^ 1][x] = *(const v4i*)(bp[x] + off);
        }
        // SWAPPED operands: C^T fragment (rows = n, cols = m)
#pragma unroll
        for (int mi = 0; mi < 4; ++mi)
#pragma unroll
            for (int ni = 0; ni < 2; ++ni)
                acc[mi][ni] = __builtin_amdgcn_mfma_i32_16x16x64_i8(
                    bF[cur][ni], aF[cur][mi], acc[mi][ni], 0, 0, 0);
    }

    // Epilogue stage 1: dequant into wave-private LDS tile [64][36].
    // C^T layout: m_local = mi*16 + (lane&15), n_local = ni*16 + 4*(lane>>4)+r.
    int cm = lane & 15;
    int qn = (lane >> 4) * 4;
#pragma unroll
    for (int mi = 0; mi < 4; ++mi) {
        int mm = m0 + wr * 64 + mi * 16 + cm;
        float sc = (mm < M) ? scales[mm] : 0.f;
#pragma unroll
        for (int ni = 0; ni < 2; ++ni) {
            int nl = ni * 16 + qn;
            v4f av = *(const v4f*)(Ascale + n0 + wc * 32 + nl);
            v4f w;
            w.x = (float)acc[mi][ni][0] * sc * av.x;
            w.y = (float)acc[mi][ni][1] * sc * av.y;
            w.z = (float)acc[mi][ni][2] * sc * av.z;
            w.w = (float)acc[mi][ni][3] * sc * av.w;
            *(v4f*)&Ct[wave][(mi * 16 + cm) * 36 + nl] = w;
        }
    }
    // Epilogue stage 2: row-major readback -> full-line nt stores.
    // lane -> row (lane>>3)+8i, cols (lane&7)*4; per instr: 8 rows x 128 B.
    int rrow = lane >> 3;
    int rcol = (lane & 7) * 4;
#pragma unroll
    for (int i = 0; i < 8; ++i) {
        int ml = rrow + 8 * i;
        v4f w = *(const v4f*)&Ct[wave][ml * 36 + rcol];
        int mm = m0 + wr * 64 + ml;
        if (mm < M)
            __builtin_nontemporal_store(
                w, (v4f*)(out + (size_t)mm * OUTF + n0 + wc * 32 + rcol));
    }
}

// ---------------------------------------------------------------------------
extern "C" void kernel_launch(void* const* d_in, const int* in_sizes, int n_in,
                              void* d_out, int out_size, void* d_ws, size_t ws_size,
                              hipStream_t stream) {
    const float* new_x  = (const float*)d_in[0];
    const float* cached = (const float*)d_in[1];
    const float* Bw     = (const float*)d_in[2];
    const int*   Ai     = (const int*)d_in[3];
    const float* Ascale = (const float*)d_in[4];

    float* out = (float*)d_out;
    float* out_latent = out + (size_t)MROWS * OUTF;

    const size_t QT_BYTES = (size_t)NGRP * 8192;        // 8,396,800
    const size_t S_BYTES  = (size_t)MROWS * sizeof(float);
    uint8_t* Qt     = (uint8_t*)d_ws;
    float*   scales = (float*)((char*)d_ws + QT_BYTES);
    uint8_t* At     = (uint8_t*)((char*)d_ws + QT_BYTES + S_BYTES);

    // Merged pre-pass: new_latent (blocks 0..511) + packA (blocks 512..2559).
    k_prep<<<2560, 256, 0, stream>>>(new_x, Bw, out_latent, Ai, At);
    k_quant<<<SROWS, 256, 0, stream>>>(cached, out_latent, Qt, scales);
    int nt_m = (MROWS + BM - 1) / BM;   // 129
    k_gemm<<<nt_m * NT_N, 256, 0, stream>>>(Qt, At, scales, Ascale, out, MROWS);
}